// Round 15
// baseline (493.278 us; speedup 1.0000x reference)
//
#include <hip/hip_runtime.h>
#include <stdint.h>
#include <string.h>
#include <stdlib.h>

#define JAX_PARTITIONABLE 1

namespace {

constexpr int kW = 45, kH = 30, kD = 13;
constexpr int NVID = kW * kH * kD;          // 17550
constexpr int TEXT = 226;
constexpr int LSEQ = TEXT + NVID;           // 17776
constexpr int BLKSZ = 128;
constexpr int NBLK = 139;
constexpr int LPAD = NBLK * BLKSZ;          // 17792
constexpr int NKEEP = 32;
constexpr int NS = NBLK * NKEEP;            // 4448
constexpr int NH = 8;
constexpr int DD = 64;
constexpr int VLAST = LSEQ - (NBLK - 1) * BLKSZ;  // 112
constexpr float SCALE = 0.125f;
constexpr float SC2 = 0.18033688011120542f;  // SCALE * log2(e)
constexpr int MAXG = 188;

// group spaces (16-row groups)
constexpr int NGR_H = LPAD / 16;            // 1112 raw groups per head
constexpr int NRAWG = NH * NGR_H;           // 8896
constexpr int NPOOLG = NH * NBLK * 7;       // 7784
constexpr int NGALL = NRAWG + NPOOLG;       // 16680

// heavy split
constexpr int NSPLIT = 16;
constexpr int HCHUNK = (LSEQ + 63) / 64;    // 278
constexpr int CHPER = (HCHUNK + NSPLIT - 1) / NSPLIT;
constexpr int NHEAVYB = NH * 2 * NSPLIT;
constexpr int NLIGHT2 = NH * (NBLK - 2) * 2;  // 2192 (64 q-rows per block)

// ---------------- workspace layout (float units) ----------------
constexpr long SZ_RB = (long)NH * LPAD * DD / 2;    // bf16 arrays
constexpr long SZ_SH = (long)NH * NS * DD / 2;
constexpr long SZ_KPB = (long)NH * NBLK * 112 * DD / 2;
constexpr long SZ_KF = (long)NGALL * 1024 / 2;
constexpr long SZ_VF = (long)NGALL * 1024 / 2;
constexpr long SZ_PL = (long)NH * NBLK * NBLK;
constexpr long SZ_PT = (long)NH * 2 * NSPLIT * BLKSZ * DD;
constexpr long SZ_PS = (long)NH * 2 * NSPLIT * BLKSZ;
constexpr long F_QB = 0;
constexpr long F_KB = F_QB + SZ_RB;
constexpr long F_VB = F_KB + SZ_RB;
constexpr long F_SQH = F_VB + SZ_RB;
constexpr long F_SQM = F_SQH + SZ_SH;
constexpr long F_SQL = F_SQM + SZ_SH;
constexpr long F_SKH = F_SQL + SZ_SH;
constexpr long F_SKM = F_SKH + SZ_SH;
constexpr long F_SKL = F_SKM + SZ_SH;
constexpr long F_KPB = F_SKL + SZ_SH;
constexpr long F_VPB = F_KPB + SZ_KPB;
constexpr long F_KFA = F_VPB + SZ_KPB;
constexpr long F_VFA = F_KFA + SZ_KF;
constexpr long F_PL = F_VFA + SZ_VF;
constexpr long F_MK = F_PL + SZ_PL;                 // int32
constexpr long F_PT = F_MK + SZ_PL;
constexpr long F_PS = F_PT + SZ_PT;
constexpr long F_TB = F_PS + SZ_PS;                 // int32 tables
// tables: inmap[LSEQ] + dstrow[LSEQ] + qidx + kidx + duppairs[2*NVID]
constexpr int TAB_MAX = 2 * LSEQ + 2 * NH * NKEEP + 2 * NVID;

// ============================ host: gilbert =============================
// Faithful port of the PROBLEM's _gen3d (volume-deficient regular-else branch
// included). o2g keeps trailing zeros; g2o keeps zeros for missed cells.
struct Gil { int* out; int n; };
static inline int sgn_i(int v) { return (v > 0) - (v < 0); }
static inline int fd2(int a) { return a >= 0 ? a / 2 : -((-a + 1) / 2); }

static void gen3d(Gil& G, int x, int y, int z,
                  int ax, int ay, int az,
                  int bx, int by, int bz,
                  int cx, int cy, int cz) {
  int w = abs(ax + ay + az), h = abs(bx + by + bz), d = abs(cx + cy + cz);
  int dax = sgn_i(ax), day = sgn_i(ay), daz = sgn_i(az);
  int dbx = sgn_i(bx), dby = sgn_i(by), dbz = sgn_i(bz);
  int dcx = sgn_i(cx), dcy = sgn_i(cy), dcz = sgn_i(cz);
  if (h == 1 && d == 1) { for (int i = 0; i < w; i++) { G.out[G.n++] = x + kW * (y + kH * z); x += dax; y += day; z += daz; } return; }
  if (w == 1 && d == 1) { for (int i = 0; i < h; i++) { G.out[G.n++] = x + kW * (y + kH * z); x += dbx; y += dby; z += dbz; } return; }
  if (w == 1 && h == 1) { for (int i = 0; i < d; i++) { G.out[G.n++] = x + kW * (y + kH * z); x += dcx; y += dcy; z += dcz; } return; }
  int ax2 = fd2(ax), ay2 = fd2(ay), az2 = fd2(az);
  int bx2 = fd2(bx), by2 = fd2(by), bz2 = fd2(bz);
  int cx2 = fd2(cx), cy2 = fd2(cy), cz2 = fd2(cz);
  int w2 = abs(ax2 + ay2 + az2), h2 = abs(bx2 + by2 + bz2), d2 = abs(cx2 + cy2 + cz2);
  if ((w2 & 1) && w > 2) { ax2 += dax; ay2 += day; az2 += daz; }
  if ((h2 & 1) && h > 2) { bx2 += dbx; by2 += dby; bz2 += dbz; }
  if ((d2 & 1) && d > 2) { cx2 += dcx; cy2 += dcy; cz2 += dcz; }
  if (2 * w > 3 * h && 2 * w > 3 * d) {
    gen3d(G, x, y, z, ax2, ay2, az2, bx, by, bz, cx, cy, cz);
    gen3d(G, x + ax2, y + ay2, z + az2, ax - ax2, ay - ay2, az - az2, bx, by, bz, cx, cy, cz);
  } else if (3 * h > 4 * d) {
    gen3d(G, x, y, z, bx2, by2, bz2, cx, cy, cz, ax2, ay2, az2);
    gen3d(G, x + bx2, y + by2, z + bz2, ax, ay, az, bx - bx2, by - by2, bz - bz2, cx, cy, cz);
    gen3d(G, x + (ax - dax) + (bx2 - dbx), y + (ay - day) + (by2 - dby), z + (az - daz) + (bz2 - dbz),
          -bx2, -by2, -bz2, cx, cy, cz, -(ax - ax2), -(ay - ay2), -(az - az2));
  } else if (3 * d > 4 * h) {
    gen3d(G, x, y, z, cx2, cy2, cz2, ax2, ay2, az2, bx, by, bz);
    gen3d(G, x + cx2, y + cy2, z + cz2, ax, ay, az, bx, by, bz, cx - cx2, cy - cy2, cz - cz2);
    gen3d(G, x + (ax - dax) + (cx2 - dcx), y + (ay - day) + (cy2 - dcy), z + (az - daz) + (cz2 - dcz),
          -cx2, -cy2, -cz2, -(ax - ax2), -(ay - ay2), -(az - az2), bx, by, bz);
  } else {
    gen3d(G, x, y, z, bx2, by2, bz2, cx2, cy2, cz2, ax2, ay2, az2);
    gen3d(G, x + bx2, y + by2, z + bz2, cx, cy, cz, ax2, ay2, az2, bx - bx2, by - by2, bz - bz2);
    gen3d(G, x + (bx2 - dbx) + (cx - dcx), y + (by2 - dby) + (cy - dcy), z + (bz2 - dbz) + (cz - dcz),
          ax, ay, az, -bx2, -by2, -bz2, -(cx - cx2), -(cy - cy2), -(cz - cz2));
    gen3d(G, x + (ax - dax) + bx2 + (cx - dcx), y + (ay - day) + by2 + (cy - dcy), z + (az - daz) + bz2 + (cz - dcz),
          -cx, -cy, -cz, -(ax - ax2), -(ay - ay2), -(az - az2), bx - bx2, by - by2, bz - bz2);
  }
}

// ============================ host: threefry ============================
static void tf2x32(uint32_t k0, uint32_t k1, uint32_t x0, uint32_t x1,
                   uint32_t& o0, uint32_t& o1) {
  uint32_t ks0 = k0, ks1 = k1, ks2 = k0 ^ k1 ^ 0x1BD11BDAu;
  const uint32_t ks[3] = {ks0, ks1, ks2};
  const int rot[2][4] = {{13, 15, 26, 6}, {17, 29, 16, 24}};
  x0 += ks[0]; x1 += ks[1];
  for (int i = 0; i < 5; i++) {
    for (int j = 0; j < 4; j++) {
      int rr = rot[i & 1][j];
      x0 += x1;
      x1 = (x1 << rr) | (x1 >> (32 - rr));
      x1 ^= x0;
    }
    x0 += ks[(i + 1) % 3];
    x1 += ks[(i + 2) % 3] + (uint32_t)(i + 1);
  }
  o0 = x0; o1 = x1;
}

static inline float bits_to_unit(uint32_t bits) {
  uint32_t fb = (bits >> 9) | 0x3f800000u;
  float f; memcpy(&f, &fb, 4);
  return f - 1.0f;
}

static void fill_idx(uint32_t K0, uint32_t K1, int* dst) {
  float u[NH * BLKSZ];
#if JAX_PARTITIONABLE
  for (int i = 0; i < NH * BLKSZ; i++) {
    uint32_t a, b; tf2x32(K0, K1, 0u, (uint32_t)i, a, b);
    u[i] = bits_to_unit(a ^ b);
  }
#else
  {
    const int n = NH * BLKSZ, hn = n / 2;
    for (int i = 0; i < hn; i++) {
      uint32_t a, b; tf2x32(K0, K1, (uint32_t)i, (uint32_t)(hn + i), a, b);
      u[i] = bits_to_unit(a);
      u[hn + i] = bits_to_unit(b);
    }
  }
#endif
  for (int h = 0; h < NH; h++) {
    const float* row = u + h * BLKSZ;
    bool used[BLKSZ] = {false};
    for (int r = 0; r < NKEEP; r++) {
      int best = -1; float bv = -2.0f;
      for (int g = 0; g < BLKSZ; g++)
        if (!used[g] && row[g] > bv) { bv = row[g]; best = g; }
      used[best] = true;
      dst[h * NKEEP + r] = best;
    }
  }
}

static int g_ndup = 0;

static void build_tables(int* tab) {
  static int yields[NVID];
  static int o2g_buf[NVID];
  static int g2o_buf[NVID];
  static int outg_loc[LSEQ];
  memset(o2g_buf, 0, sizeof(o2g_buf));
  memset(g2o_buf, 0, sizeof(g2o_buf));
  Gil G{yields, 0};
  gen3d(G, 0, 0, 0, kW, 0, 0, 0, kH, 0, 0, 0, kD);
  int n = G.n;
  if (n > NVID) n = NVID;
  for (int g = 0; g < n; g++) o2g_buf[g] = yields[g];
  for (int g = 0; g < n; g++) g2o_buf[yields[g]] = g;

  int* inmap = tab;                         // [LSEQ]
  int* dstrow = tab + LSEQ;                 // [LSEQ]
  int* qidx = tab + 2 * LSEQ;               // [NH*NKEEP]
  int* kidx = qidx + NH * NKEEP;            // [NH*NKEEP]
  int* duppairs = kidx + NH * NKEEP;        // [2*ndup]

  for (int g = 0; g < NVID; g++) inmap[g] = TEXT + o2g_buf[g];
  for (int t = 0; t < TEXT; t++) inmap[NVID + t] = t;
  for (int r = 0; r < TEXT; r++) outg_loc[r] = NVID + r;
  for (int c = 0; c < NVID; c++) outg_loc[TEXT + c] = g2o_buf[c];

  for (int g = 0; g < LSEQ; g++) dstrow[g] = -1;
  int nd = 0;
  for (int r = 0; r < LSEQ; r++) {
    int g = outg_loc[r];
    if (dstrow[g] < 0) dstrow[g] = r;
    else { duppairs[2 * nd] = r; duppairs[2 * nd + 1] = dstrow[g]; nd++; }
  }
  g_ndup = nd;

  uint32_t kq0, kq1, kk0, kk1;
#if JAX_PARTITIONABLE
  tf2x32(0, 0, 0, 0, kq0, kq1);
  tf2x32(0, 0, 0, 1, kk0, kk1);
#else
  {
    uint32_t y00, y10, y01, y11;
    tf2x32(0, 0, 0, 2, y00, y10);
    tf2x32(0, 0, 1, 3, y01, y11);
    kq0 = y00; kq1 = y01; kk0 = y10; kk1 = y11;
  }
#endif
  fill_idx(kq0, kq1, qidx);
  fill_idx(kk0, kk1, kidx);
}

}  // namespace

// ============================ device helpers ============================

typedef __attribute__((ext_vector_type(8))) short short8v;
typedef __attribute__((ext_vector_type(4))) float f32x4;

static __device__ inline unsigned short f2bf(float f) {
  unsigned u = __float_as_uint(f);
  unsigned r = u + 0x7FFFu + ((u >> 16) & 1u);  // RNE
  return (unsigned short)(r >> 16);
}
static __device__ inline float bf2f(unsigned short s) {
  return __uint_as_float(((unsigned)s) << 16);
}
static __device__ inline int cvtpk(float lo, float hi) {
  int r;
  asm("v_cvt_pk_bf16_f32 %0, %1, %2" : "=v"(r) : "v"(lo), "v"(hi));
  return r;
}

struct KFrag {
  short8v h[2][2], m[2][2], l[2][2];
};

// ============================ device kernels ============================

// rearrange -> bf16 row-major arrays (b128 writes)
__global__ __launch_bounds__(256) void k_rearr(
    const float* __restrict__ q, const float* __restrict__ k, const float* __restrict__ v,
    short* __restrict__ qrb, short* __restrict__ krb, short* __restrict__ vrb,
    const int* __restrict__ inmap) {
  long gid = (long)blockIdx.x * 256 + threadIdx.x;
  const long totalRows = 3L * NH * LPAD;
  long rowid = gid >> 3;
  int g8 = (int)(gid & 7);
  if (rowid >= totalRows) return;
  int tsel = (int)(rowid / ((long)NH * LPAD));
  long rem = rowid - (long)tsel * NH * LPAD;
  int h = (int)(rem / LPAD);
  int i = (int)(rem % LPAD);
  const float* src = tsel == 0 ? q : (tsel == 1 ? k : v);
  short8v outv;
  if (i < LSEQ) {
    const float* sp = src + ((long)h * LSEQ + inmap[i]) * DD + g8 * 8;
    float4 a = *(const float4*)sp;
    float4 b = *(const float4*)(sp + 4);
    float vals[8] = {a.x, a.y, a.z, a.w, b.x, b.y, b.z, b.w};
#pragma unroll
    for (int j = 0; j < 8; j++) outv[j] = (short)f2bf(vals[j]);
  } else {
#pragma unroll
    for (int j = 0; j < 8; j++) outv[j] = 0;
  }
  short* dst = tsel == 0 ? qrb : (tsel == 1 ? krb : vrb);
  *(short8v*)(dst + ((long)h * LPAD + i) * DD + g8 * 8) = outv;
}

// sampled q/k rows -> fragment-major 3-way bf16 split arrays
__global__ __launch_bounds__(256) void k_sample(
    const float* __restrict__ q, const float* __restrict__ k,
    short* __restrict__ sqh, short* __restrict__ sqm, short* __restrict__ sql,
    short* __restrict__ skh, short* __restrict__ skm, short* __restrict__ skl,
    const int* __restrict__ qidx, const int* __restrict__ kidx,
    const int* __restrict__ inmap) {
  long gid = (long)blockIdx.x * 256 + threadIdx.x;
  int g = (int)(gid & 7);
  long rowid = gid >> 3;
  const long half = (long)NH * NS;
  if (rowid >= 2 * half) return;
  int tsel = rowid >= half;
  long rem = tsel ? rowid - half : rowid;
  int h = (int)(rem / NS);
  int s = (int)(rem % NS);
  int b = s / NKEEP, t = s % NKEEP;
  const int* idx = tsel ? kidx : qidx;
  int p = b * BLKSZ + idx[h * NKEEP + t];
  if (p >= LSEQ) p = LSEQ - 1;
  int orig = inmap[p];
  const float* src = (tsel ? k : q) + ((long)h * LSEQ + orig) * DD + g * 8;
  float4 a = *(const float4*)src;
  float4 bb = *(const float4*)(src + 4);
  float vals[8] = {a.x, a.y, a.z, a.w, bb.x, bb.y, bb.z, bb.w};
  short8v vh, vm, vl;
#pragma unroll
  for (int j = 0; j < 8; j++) {
    unsigned short hi = f2bf(vals[j]);
    float r1 = vals[j] - bf2f(hi);
    unsigned short mi = f2bf(r1);
    float r2 = r1 - bf2f(mi);
    unsigned short lo = f2bf(r2);
    vh[j] = (short)hi; vm[j] = (short)mi; vl[j] = (short)lo;
  }
  int t16 = s >> 4, lm = s & 15, ks = g >> 2, lg = g & 3;
  long off = (long)h * NS * DD + ((long)(t16 * 2 + ks)) * 512 + (lg * 16 + lm) * 8;
  if (tsel) {
    *(short8v*)(skh + off) = vh;
    *(short8v*)(skm + off) = vm;
    *(short8v*)(skl + off) = vl;
  } else {
    *(short8v*)(sqh + off) = vh;
    *(short8v*)(sqm + off) = vm;
    *(short8v*)(sql + off) = vl;
  }
}

static __device__ inline void ld_frags(
    const short* __restrict__ skh, const short* __restrict__ skm,
    const short* __restrict__ skl, long kbase, int c, int lane, KFrag& F) {
#pragma unroll
  for (int nt = 0; nt < 2; nt++)
#pragma unroll
    for (int ks = 0; ks < 2; ks++) {
      long a = kbase + ((long)((2 * c + nt) * 2 + ks)) * 512 + lane * 8;
      F.h[nt][ks] = *(const short8v*)(skh + a);
      F.m[nt][ks] = *(const short8v*)(skm + a);
      F.l[nt][ks] = *(const short8v*)(skl + a);
    }
}

// scores+pool: fragment-direct, split-bf16 6-term MFMA. bid&7 = head.
__global__ __launch_bounds__(256, 2) void k_scores_pool(
    const short* __restrict__ sqh, const short* __restrict__ sqm, const short* __restrict__ sql,
    const short* __restrict__ skh, const short* __restrict__ skm, const short* __restrict__ skl,
    float* __restrict__ pool) {
  __shared__ float bins[32][145];
  __shared__ float invden[32];
  int bid = blockIdx.x;
  int h = bid & 7, qb = bid >> 3;
  int tid = threadIdx.x;
  int wid = tid >> 6, lane = tid & 63;
  int lm = lane & 15, lg = lane >> 4;

  for (int i = tid; i < 32 * 145; i += 256) (&bins[0][0])[i] = 0.f;

  const long base = (long)h * NS * DD;
  short8v Qh[2][2], Qm[2][2], Ql[2][2];
#pragma unroll
  for (int mt = 0; mt < 2; mt++)
#pragma unroll
    for (int ks = 0; ks < 2; ks++) {
      long off = base + ((long)((2 * qb + mt) * 2 + ks)) * 512 + lane * 8;
      Qh[mt][ks] = *(const short8v*)(sqh + off);
      Qm[mt][ks] = *(const short8v*)(sqm + off);
      Ql[mt][ks] = *(const short8v*)(sql + off);
    }
  __syncthreads();

  auto compute = [&](const KFrag& F, int c) {
    f32x4 aq[2][2];
#pragma unroll
    for (int mt = 0; mt < 2; mt++)
#pragma unroll
      for (int nt = 0; nt < 2; nt++) {
        f32x4 a = {0.f, 0.f, 0.f, 0.f};
#pragma unroll
        for (int ks = 0; ks < 2; ks++) {
          a = __builtin_amdgcn_mfma_f32_16x16x32_bf16(F.h[nt][ks], Qh[mt][ks], a, 0, 0, 0);
          a = __builtin_amdgcn_mfma_f32_16x16x32_bf16(F.h[nt][ks], Qm[mt][ks], a, 0, 0, 0);
          a = __builtin_amdgcn_mfma_f32_16x16x32_bf16(F.m[nt][ks], Qh[mt][ks], a, 0, 0, 0);
          a = __builtin_amdgcn_mfma_f32_16x16x32_bf16(F.m[nt][ks], Qm[mt][ks], a, 0, 0, 0);
          a = __builtin_amdgcn_mfma_f32_16x16x32_bf16(F.h[nt][ks], Ql[mt][ks], a, 0, 0, 0);
          a = __builtin_amdgcn_mfma_f32_16x16x32_bf16(F.l[nt][ks], Qh[mt][ks], a, 0, 0, 0);
        }
        aq[mt][nt] = a;
      }
#pragma unroll
    for (int mt = 0; mt < 2; mt++) {
      float s = 0.f;
#pragma unroll
      for (int nt = 0; nt < 2; nt++)
#pragma unroll
        for (int i = 0; i < 4; i++)
          s += __expf(aq[mt][nt][i] * SCALE);
      s += __shfl_xor(s, 16);
      s += __shfl_xor(s, 32);
      if (lg == 0) bins[mt * 16 + lm][c] += s;
    }
  };

  KFrag A, B;
  ld_frags(skh, skm, skl, base, wid, lane, A);
  for (int c = wid; c < NBLK; c += 8) {
    if (c + 4 < NBLK) ld_frags(skh, skm, skl, base, c + 4, lane, B);
    compute(A, c);
    if (c + 4 >= NBLK) break;
    if (c + 8 < NBLK) ld_frags(skh, skm, skl, base, c + 8, lane, A);
    compute(B, c + 4);
  }

  __syncthreads();
  if (tid < 32) {
    float s = 0.f;
    for (int kb = 0; kb < NBLK; kb++) s += bins[tid][kb];
    invden[tid] = 1.0f / s;
  }
  __syncthreads();
  if (tid < NBLK) {
    float s = 0.f;
    for (int r2 = 0; r2 < NKEEP; r2++) s += bins[r2][tid] * invden[r2];
    pool[((long)h * NBLK + qb) * NBLK + tid] = s;
  }
}

__global__ __launch_bounds__(192) void k_mask(
    const float* __restrict__ pool, int* __restrict__ mask) {
  __shared__ float row[NBLK];
  int h = blockIdx.x / NBLK, i = blockIdx.x % NBLK;
  int t = threadIdx.x;
  const float* pr = pool + ((long)h * NBLK + i) * NBLK;
  if (t < NBLK) row[t] = pr[t];
  __syncthreads();
  if (t < NBLK) {
    float pv = row[t];
    int rank = 0;
    for (int j = 0; j < NBLK; j++) {
      float o = row[j];
      rank += (o > pv) || (o == pv && j < t);
    }
    int val = 0;
    if (rank < 6) val = 1;
    else if (rank < 20) val = 2;
    else if (rank < 34) val = 4;
    else if (rank < 69) val = 8;
    if (t >= NBLK - 2) val = 1;
    if (i >= NBLK - 2) val = 1;
    mask[((long)h * NBLK + i) * NBLK + t] = val;
  }
}

__global__ __launch_bounds__(256) void k_poolkv(
    const short* __restrict__ krb, const short* __restrict__ vrb,
    short* __restrict__ Kpb, short* __restrict__ Vpb) {
  long rid = (long)blockIdx.x * 4 + (threadIdx.x >> 6);
  int d = threadIdx.x & 63;
  const long total = 2L * NH * NBLK * 112;
  if (rid >= total) return;
  int tsel = (int)(rid / ((long)NH * NBLK * 112));
  long rem = rid - (long)tsel * NH * NBLK * 112;
  int h = (int)(rem / (NBLK * 112));
  int rem2 = (int)(rem % (NBLK * 112));
  int j = rem2 / 112, p = rem2 % 112;
  int m, g;
  if (p < 64) { m = 2; g = p; }
  else if (p < 96) { m = 4; g = p - 64; }
  else { m = 8; g = p - 96; }
  const short* src = tsel ? vrb : krb;
  const short* base = src + ((long)h * LPAD + j * BLKSZ + g * m) * DD + d;
  float sum = 0.f;
  for (int r2 = 0; r2 < m; r2++) sum += bf2f((unsigned short)base[(long)r2 * DD]);
  short* dst = tsel ? Vpb : Kpb;
  dst[(((long)h * NBLK + j) * 112 + p) * DD + d] = (short)f2bf(sum / (float)m);
}

// fragment-major K builder
__global__ __launch_bounds__(256) void k_fragk(
    const short* __restrict__ krb, const short* __restrict__ Kpb,
    short* __restrict__ kfAll) {
  long gid = (long)blockIdx.x * 256 + threadIdx.x;
  if (gid >= (long)NGALL * 128) return;
  int lane = (int)(gid & 63);
  int ks = (int)((gid >> 6) & 1);
  long grp = gid >> 7;
  int lm = lane & 15, lg = lane >> 4;
  const short* srcp;
  long row;
  if (grp < NRAWG) { srcp = krb; row = grp * 16 + lm; }
  else { srcp = Kpb; row = (grp - NRAWG) * 16 + lm; }
  short8v vv = *(const short8v*)(srcp + row * DD + ks * 32 + lg * 8);
  *(short8v*)(kfAll + ((long)grp * 2 + ks) * 512 + lane * 8) = vv;
}

// fragment-major V^T builder
__global__ __launch_bounds__(256) void k_fragv(
    const short* __restrict__ vrb, const short* __restrict__ Vpb,
    short* __restrict__ vfAll) {
  long gid = (long)blockIdx.x * 256 + threadIdx.x;
  if (gid >= (long)NGALL * 256) return;
  int lane = (int)(gid & 63);
  int mtp = (int)((gid >> 6) & 3);
  long grp = gid >> 8;
  int lm = lane & 15, lg = lane >> 4;
  const short* srcp;
  long rowb;
  if (grp < NRAWG) { srcp = vrb; rowb = grp * 16 + lg * 4; }
  else { srcp = Vpb; rowb = (grp - NRAWG) * 16 + lg * 4; }
  short4 o;
  o.x = srcp[(rowb + 0) * DD + mtp * 16 + lm];
  o.y = srcp[(rowb + 1) * DD + mtp * 16 + lm];
  o.z = srcp[(rowb + 2) * DD + mtp * 16 + lm];
  o.w = srcp[(rowb + 3) * DD + mtp * 16 + lm];
  *(short4*)(vfAll + ((long)grp * 4 + mtp) * 256 + lane * 4) = o;
}

// ---------- LIGHT attention: 64 q-rows/block, double-buffered LDS ----------
// One barrier per chunk; direct-scatter output via dstrow.
__global__ __launch_bounds__(256, 2) void k_attn_light(
    const short* __restrict__ qrb,
    const short* __restrict__ kfAll, const short* __restrict__ vfAll,
    const int* __restrict__ mask, const int* __restrict__ dstrow,
    float* __restrict__ out) {
  __shared__ int glist[MAXG];
  __shared__ int wtot[4];
  __shared__ int smeta;
  __shared__ __align__(16) short KtF[2][4096];
  __shared__ __align__(16) short VtF[2][4096];

  int bid = blockIdx.x;
  int half = bid & 1;
  int lb = bid >> 1;
  int h = lb / (NBLK - 2);
  int qi = lb % (NBLK - 2);
  int tid = threadIdx.x;
  int lane = tid & 63, wid = tid >> 6;
  int lm = lane & 15, lg = lane >> 4;

  // per-column group counts + shfl scan
  int myng = 0, mylvl = 0, myG = 0;
  if (tid < NBLK) {
    int mv = mask[((long)h * NBLK + qi) * NBLK + tid];
    if (mv) {
      mylvl = (mv == 1) ? 0 : (mv == 2) ? 1 : (mv == 4) ? 2 : 3;
      myG = ((tid == NBLK - 1) ? VLAST : BLKSZ) >> mylvl;
      myng = (myG + 15) >> 4;
    }
  }
  int v = myng;
#pragma unroll
  for (int off = 1; off < 64; off <<= 1) {
    int t2 = __shfl_up(v, off);
    if ((tid & 63) >= off) v += t2;
  }
  if ((tid & 63) == 63) wtot[wid] = v;
  __syncthreads();
  int woff = 0;
#pragma unroll
  for (int w = 0; w < 4; w++) if (w < wid) woff += wtot[w];
  int myoff = woff + v - myng;
  if (tid == 0) {
    int tot = wtot[0] + wtot[1] + wtot[2] + wtot[3];
    while (tot & 3) glist[tot++] = 0;
    smeta = tot >> 2;
  }
  __syncthreads();
  if (tid < NBLK && myng) {
    int grp0;
    if (mylvl == 0) grp0 = h * NGR_H + tid * 8;
    else {
      int l16 = (mylvl == 1) ? 0 : (mylvl == 2) ? 4 : 6;
      grp0 = NRAWG + (h * NBLK + tid) * 7 + l16;
    }
    for (int g = 0; g < myng; g++) {
      int cnt = myG - 16 * g; if (cnt > 16) cnt = 16;
      glist[myoff + g] = (grp0 + g) | (cnt << 24) | (mylvl << 29);
    }
  }
  __syncthreads();
  int nchunks = smeta;

  // Q fragments (16 rows per wave)
  short8v Qf[2];
  {
    long row = (long)h * LPAD + qi * BLKSZ + half * 64 + wid * 16 + lm;
    Qf[0] = *(const short8v*)(qrb + row * DD + lg * 8);
    Qf[1] = *(const short8v*)(qrb + row * DD + 32 + lg * 8);
  }
  short8v onesv;
#pragma unroll
  for (int j = 0; j < 8; j++) onesv[j] = (short)0x3F80;  // bf16 1.0
  f32x4 Oacc[4];
#pragma unroll
  for (int a = 0; a < 4; a++) { f32x4 z = {0.f, 0.f, 0.f, 0.f}; Oacc[a] = z; }
  f32x4 Oden = {0.f, 0.f, 0.f, 0.f};

  // staging regs
  short8v rk0, rk1, rv0, rv1;
  auto ldStage = [&](int c) {
    {
      int s = tid;
      long grp = (long)((unsigned)glist[4 * c + (s >> 7)] & 0xFFFFFFu);
      rk0 = *(const short8v*)(kfAll + (grp * 2 + ((s >> 6) & 1)) * 512 + (long)(s & 63) * 8);
      s = tid + 256;
      grp = (long)((unsigned)glist[4 * c + (s >> 7)] & 0xFFFFFFu);
      rk1 = *(const short8v*)(kfAll + (grp * 2 + ((s >> 6) & 1)) * 512 + (long)(s & 63) * 8);
    }
    {
      int s = tid;
      long grp = (long)((unsigned)glist[4 * c + (s >> 7)] & 0xFFFFFFu);
      rv0 = *(const short8v*)(vfAll + (grp * 4 + ((s >> 5) & 3)) * 256 + (long)(s & 31) * 8);
      s = tid + 256;
      grp = (long)((unsigned)glist[4 * c + (s >> 7)] & 0xFFFFFFu);
      rv1 = *(const short8v*)(vfAll + (grp * 4 + ((s >> 5) & 3)) * 256 + (long)(s & 31) * 8);
    }
  };
  auto stStage = [&](int wb) {
    *(short8v*)&KtF[wb][tid * 8] = rk0;
    *(short8v*)&KtF[wb][(tid + 256) * 8] = rk1;
    {
      int s = tid;
      int g = s >> 7, mtp = (s >> 5) & 3, l = s & 31;
      int base = (mtp * 2 + (g >> 1)) * 512 + ((g & 1) * 4) + l * 16;
      *(short4*)&VtF[wb][base] = make_short4(rv0[0], rv0[1], rv0[2], rv0[3]);
      *(short4*)&VtF[wb][base + 8] = make_short4(rv0[4], rv0[5], rv0[6], rv0[7]);
      s = tid + 256;
      g = s >> 7; mtp = (s >> 5) & 3; l = s & 31;
      base = (mtp * 2 + (g >> 1)) * 512 + ((g & 1) * 4) + l * 16;
      *(short4*)&VtF[wb][base] = make_short4(rv1[0], rv1[1], rv1[2], rv1[3]);
      *(short4*)&VtF[wb][base + 8] = make_short4(rv1[4], rv1[5], rv1[6], rv1[7]);
    }
  };

  // prologue: stage chunk 0 into buf 0
  ldStage(0);
  stStage(0);
  __syncthreads();
  int buf = 0;

  for (int c = 0; c < nchunks; c++) {
    // stage chunk c+1 into the other buffer (no reader conflict: its last
    // readers finished before the barrier at the end of iteration c-1)
    if (c + 1 < nchunks) {
      ldStage(c + 1);
      stStage(buf ^ 1);
    }

    int cntv[4]; float biasv[4];
#pragma unroll
    for (int g = 0; g < 4; g++) {
      unsigned e = (unsigned)glist[4 * c + g];
      cntv[g] = (e >> 24) & 31;
      biasv[g] = (float)((e >> 29) & 3);   // exp2-domain bias = lvl
    }
    bool allfull = (cntv[0] == 16) & (cntv[1] == 16) & (cntv[2] == 16) & (cntv[3] == 16);

    // QK^T
    f32x4 aq[4];
#pragma unroll
    for (int nt = 0; nt < 4; nt++) {
      short8v k0 = *(short8v*)&KtF[buf][(nt * 2 + 0) * 512 + lane * 8];
      short8v k1 = *(short8v*)&KtF[buf][(nt * 2 + 1) * 512 + lane * 8];
      f32x4 z = {0.f, 0.f, 0.f, 0.f};
      f32x4 a = __builtin_amdgcn_mfma_f32_16x16x32_bf16(k0, Qf[0], z, 0, 0, 0);
      aq[nt] = __builtin_amdgcn_mfma_f32_16x16x32_bf16(k1, Qf[1], a, 0, 0, 0);
    }
    // softmax
    float ps[16];
    if (allfull) {
#pragma unroll
      for (int nt = 0; nt < 4; nt++)
#pragma unroll
        for (int i = 0; i < 4; i++)
          ps[nt * 4 + i] = exp2f(fmaf(aq[nt][i], SC2, biasv[nt]));
    } else {
#pragma unroll
      for (int nt = 0; nt < 4; nt++)
#pragma unroll
        for (int i = 0; i < 4; i++) {
          int kvr = lg * 4 + i;
          ps[nt * 4 + i] = (kvr < cntv[nt]) ? exp2f(fmaf(aq[nt][i], SC2, biasv[nt])) : 0.f;
        }
    }
    short8v Pf[2];
#pragma unroll
    for (int H = 0; H < 2; H++) {
      union { int i[4]; short8v v; } u;
      u.i[0] = cvtpk(ps[8 * H + 0], ps[8 * H + 1]);
      u.i[1] = cvtpk(ps[8 * H + 2], ps[8 * H + 3]);
      u.i[2] = cvtpk(ps[8 * H + 4], ps[8 * H + 5]);
      u.i[3] = cvtpk(ps[8 * H + 6], ps[8 * H + 7]);
      Pf[H] = u.v;
    }
    // denominator on the MFMA pipe (ones-column trick)
    Oden = __builtin_amdgcn_mfma_f32_16x16x32_bf16(onesv, Pf[0], Oden, 0, 0, 0);
    Oden = __builtin_amdgcn_mfma_f32_16x16x32_bf16(onesv, Pf[1], Oden, 0, 0, 0);
    // PV (paired layout: b128 reads)
#pragma unroll
    for (int mtp = 0; mtp < 4; mtp++) {
      short8v vf0 = *(short8v*)&VtF[buf][(mtp * 2 + 0) * 512 + lane * 8];
      short8v vf1 = *(short8v*)&VtF[buf][(mtp * 2 + 1) * 512 + lane * 8];
      Oacc[mtp] = __builtin_amdgcn_mfma_f32_16x16x32_bf16(vf0, Pf[0], Oacc[mtp], 0, 0, 0);
      Oacc[mtp] = __builtin_amdgcn_mfma_f32_16x16x32_bf16(vf1, Pf[1], Oacc[mtp], 0, 0, 0);
    }
    __syncthreads();   // readers of buf done; writers of buf^1 done
    buf ^= 1;
  }

  float inv = 1.0f / Oden[0];
  {
    int grow = qi * BLKSZ + half * 64 + wid * 16 + lm;
    int dr = dstrow[grow];
    if (dr >= 0) {
      float* orow = out + ((long)h * LSEQ + dr) * DD;
#pragma unroll
      for (int mtp = 0; mtp < 4; mtp++) {
        f32x4 o = Oacc[mtp];
        *(float4*)(orow + mtp * 16 + lg * 4) =
            make_float4(o[0] * inv, o[1] * inv, o[2] * inv, o[3] * inv);
      }
    }
  }
}

// ---------------- HEAVY (full-attn) q-blocks ----------------
__global__ __launch_bounds__(256, 1) void k_attn_heavy(
    const short* __restrict__ qrb, const short* __restrict__ krb,
    const short* __restrict__ vrb,
    float* __restrict__ part, float* __restrict__ plsum) {
  __shared__ __align__(16) short Kt[64 * 64];
  __shared__ __align__(16) short Vt[64 * 68];

  int bid = blockIdx.x;
  int split = bid & (NSPLIT - 1);
  int hq = bid / NSPLIT;
  int h = hq >> 1;
  int qi = NBLK - 2 + (hq & 1);
  int c0 = split * CHPER;
  int c1 = c0 + CHPER; if (c1 > HCHUNK) c1 = HCHUNK;
  int slot = hq * NSPLIT + split;
  int tid = threadIdx.x;

  int lane = tid & 63, wid = tid >> 6;
  int lm = lane & 15, lg = lane >> 4;

  short8v Qf[2][2];
#pragma unroll
  for (int mt = 0; mt < 2; mt++)
#pragma unroll
    for (int ks = 0; ks < 2; ks++) {
      long row = (long)h * LPAD + qi * BLKSZ + wid * 32 + mt * 16 + lm;
      Qf[mt][ks] = *(const short8v*)(qrb + row * DD + ks * 32 + lg * 8);
    }

  f32x4 Oacc[4][2];
#pragma unroll
  for (int a = 0; a < 4; a++)
#pragma unroll
    for (int b = 0; b < 2; b++) { f32x4 z = {0.f, 0.f, 0.f, 0.f}; Oacc[a][b] = z; }
  float lrow0 = 0.f, lrow1 = 0.f;

  int sr = tid & 63;
  int sd0 = (tid >> 6) * 16;

  short8v pkA, pkB, pvA, pvB;
  {
    long src = (long)h * LPAD + (long)c0 * 64 + sr;
    const short8v* kp = (const short8v*)(krb + src * DD + sd0);
    const short8v* vp = (const short8v*)(vrb + src * DD + sd0);
    pkA = kp[0]; pkB = kp[1];
    pvA = vp[0]; pvB = vp[1];
  }

  for (int c = c0; c < c1; c++) {
    __syncthreads();
    {
      int sw = (sr & 7) << 3;
      *(short8v*)&Kt[sr * 64 + (sd0 ^ sw)] = pkA;
      *(short8v*)&Kt[sr * 64 + ((sd0 + 8) ^ sw)] = pkB;
#pragma unroll
      for (int i = 0; i < 8; i++) {
        Vt[(sd0 + i) * 68 + sr] = pvA[i];
        Vt[(sd0 + 8 + i) * 68 + sr] = pvB[i];
      }
    }
    __syncthreads();
    if (c + 1 < c1) {
      long src = (long)h * LPAD + (long)(c + 1) * 64 + sr;
      const short8v* kp = (const short8v*)(krb + src * DD + sd0);
      const short8v* vp = (const short8v*)(vrb + src * DD + sd0);
      pkA = kp[0]; pkB = kp[1];
      pvA = vp[0]; pvB = vp[1];
    }

    bool allfull = (c != HCHUNK - 1);

    short8v Kf[4][2];
#pragma unroll
    for (int nt = 0; nt < 4; nt++)
#pragma unroll
      for (int ks = 0; ks < 2; ks++)
        Kf[nt][ks] = *(short8v*)&Kt[(nt * 16 + lm) * 64 + ((ks * 32 + lg * 8) ^ ((lm & 7) << 3))];

    short8v Pf[2][2];
#pragma unroll
    for (int mt = 0; mt < 2; mt++) {
      f32x4 aq[4];
#pragma unroll
      for (int nt = 0; nt < 4; nt++) {
        f32x4 z = {0.f, 0.f, 0.f, 0.f};
        f32x4 a = __builtin_amdgcn_mfma_f32_16x16x32_bf16(Kf[nt][0], Qf[mt][0], z, 0, 0, 0);
        aq[nt] = __builtin_amdgcn_mfma_f32_16x16x32_bf16(Kf[nt][1], Qf[mt][1], a, 0, 0, 0);
      }
      float ps[16];
      if (allfull) {
#pragma unroll
        for (int nt = 0; nt < 4; nt++)
#pragma unroll
          for (int i = 0; i < 4; i++)
            ps[nt * 4 + i] = __expf(aq[nt][i] * SCALE);
      } else {
#pragma unroll
        for (int nt = 0; nt < 4; nt++) {
          int cc = LSEQ - 16 * (4 * c + nt);
          int cnt = cc <= 0 ? 0 : (cc >= 16 ? 16 : cc);
#pragma unroll
          for (int i = 0; i < 4; i++) {
            int kvr = lg * 4 + i;
            ps[nt * 4 + i] = (kvr < cnt) ? __expf(aq[nt][i] * SCALE) : 0.f;
          }
        }
      }
      float lsum = 0.f;
#pragma unroll
      for (int i = 0; i < 16; i++) lsum += ps[i];
      if (mt == 0) lrow0 += lsum; else lrow1 += lsum;
#pragma unroll
      for (int H = 0; H < 2; H++) {
        union { int i[4]; short8v v; } u;
        u.i[0] = cvtpk(ps[8 * H + 0], ps[8 * H + 1]);
        u.i[1] = cvtpk(ps[8 * H + 2], ps[8 * H + 3]);
        u.i[2] = cvtpk(ps[8 * H + 4], ps[8 * H + 5]);
        u.i[3] = cvtpk(ps[8 * H + 6], ps[8 * H + 7]);
        Pf[mt][H] = u.v;
      }
    }

#pragma unroll
    for (int mtp = 0; mtp < 4; mtp++) {
      int d68 = (mtp * 16 + lm) * 68;
#pragma unroll
      for (int H = 0; H < 2; H++) {
        short4 lo = *(short4*)&Vt[d68 + H * 32 + lg * 4];
        short4 hi = *(short4*)&Vt[d68 + H * 32 + 16 + lg * 4];
        short8v vf;
        vf[0] = lo.x; vf[1] = lo.y; vf[2] = lo.z; vf[3] = lo.w;
        vf[4] = hi.x; vf[5] = hi.y; vf[6] = hi.z; vf[7] = hi.w;
        Oacc[mtp][0] = __builtin_amdgcn_mfma_f32_16x16x32_bf16(vf, Pf[0][H], Oacc[mtp][0], 0, 0, 0);
        Oacc[mtp][1] = __builtin_amdgcn_mfma_f32_16x16x32_bf16(vf, Pf[1][H], Oacc[mtp][1], 0, 0, 0);
      }
    }
  }

  lrow0 += __shfl_xor(lrow0, 16); lrow0 += __shfl_xor(lrow0, 32);
  lrow1 += __shfl_xor(lrow1, 16); lrow1 += __shfl_xor(lrow1, 32);
  if (lg == 0) {
    plsum[(long)slot * BLKSZ + wid * 32 + lm] = lrow0;
    plsum[(long)slot * BLKSZ + wid * 32 + 16 + lm] = lrow1;
  }
#pragma unroll
  for (int mt = 0; mt < 2; mt++) {
    int lrow = wid * 32 + mt * 16 + lm;
    float* orow = part + ((long)slot * BLKSZ + lrow) * DD;
#pragma unroll
    for (int mtp = 0; mtp < 4; mtp++) {
      f32x4 o = Oacc[mtp][mt];
      *(float4*)(orow + mtp * 16 + lg * 4) = make_float4(o[0], o[1], o[2], o[3]);
    }
  }
}

// combine heavy partials -> out directly (via dstrow)
__global__ __launch_bounds__(256) void k_combine(
    const float* __restrict__ part, const float* __restrict__ plsum,
    const int* __restrict__ dstrow, float* __restrict__ out) {
  int hq = blockIdx.x;
  int h = hq >> 1;
  int qi = NBLK - 2 + (hq & 1);
  int t = threadIdx.x;
  int row = t >> 1;
  int dbase = (t & 1) * 32;
  float l = 0.f;
  for (int s = 0; s < NSPLIT; s++) l += plsum[(long)(hq * NSPLIT + s) * BLKSZ + row];
  int grow = qi * BLKSZ + row;
  if (grow >= LSEQ) return;
  int dr = dstrow[grow];
  if (dr < 0) return;
  float inv = 1.0f / l;
  float* orow = out + ((long)h * LSEQ + dr) * DD;
  for (int d = dbase; d < dbase + 32; d += 4) {
    float4 acc = make_float4(0.f, 0.f, 0.f, 0.f);
    for (int s = 0; s < NSPLIT; s++) {
      float4 p4 = *(const float4*)&part[((long)(hq * NSPLIT + s) * BLKSZ + row) * DD + d];
      acc.x += p4.x; acc.y += p4.y; acc.z += p4.z; acc.w += p4.w;
    }
    *(float4*)(orow + d) = make_float4(acc.x * inv, acc.y * inv, acc.z * inv, acc.w * inv);
  }
}

// duplicate-row fixup: out[h][dst] = out[h][src] for host-built pairs
__global__ __launch_bounds__(64) void k_fixup(
    const int* __restrict__ duppairs, float* __restrict__ out, int nd) {
  int bid = blockIdx.x;       // dup*NH + h
  int h = bid & (NH - 1);
  int dup = bid >> 3;
  if (dup >= nd) return;
  int rdst = duppairs[2 * dup];
  int rsrc = duppairs[2 * dup + 1];
  out[((long)h * LSEQ + rdst) * DD + threadIdx.x] =
      out[((long)h * LSEQ + rsrc) * DD + threadIdx.x];
}

// ============================ launch ============================

extern "C" void kernel_launch(void* const* d_in, const int* in_sizes, int n_in,
                              void* d_out, int out_size, void* d_ws, size_t ws_size,
                              hipStream_t stream) {
  (void)in_sizes; (void)n_in; (void)out_size; (void)ws_size;
  const float* q = (const float*)d_in[0];
  const float* k = (const float*)d_in[1];
  const float* v = (const float*)d_in[2];
  float* ws = (float*)d_ws;
  float* out = (float*)d_out;

  static int* htab = nullptr;
  if (!htab) { (void)hipHostMalloc((void**)&htab, TAB_MAX * sizeof(int)); }
  build_tables(htab);
  int ndup = g_ndup;

  int* dtab = (int*)(ws + F_TB);
  int* inmap = dtab;
  int* dstrow = dtab + LSEQ;
  int* qidx = dtab + 2 * LSEQ;
  int* kidx = qidx + NH * NKEEP;
  int* duppairs = kidx + NH * NKEEP;
  int* dmask = (int*)(ws + F_MK);
  short* qrb = (short*)(ws + F_QB);
  short* krb = (short*)(ws + F_KB);
  short* vrb = (short*)(ws + F_VB);
  short* sqh = (short*)(ws + F_SQH);
  short* sqm = (short*)(ws + F_SQM);
  short* sql = (short*)(ws + F_SQL);
  short* skh = (short*)(ws + F_SKH);
  short* skm = (short*)(ws + F_SKM);
  short* skl = (short*)(ws + F_SKL);
  short* Kpb = (short*)(ws + F_KPB);
  short* Vpb = (short*)(ws + F_VPB);
  short* kfAll = (short*)(ws + F_KFA);
  short* vfAll = (short*)(ws + F_VFA);
  float* pool = ws + F_PL;
  float* part = ws + F_PT;
  float* plsum = ws + F_PS;

  hipMemcpyAsync(dtab, htab,
                 (size_t)(2 * LSEQ + 2 * NH * NKEEP + 2 * ndup) * sizeof(int),
                 hipMemcpyHostToDevice, stream);

  {
    long thr = 3L * NH * LPAD * 8;
    k_rearr<<<dim3((unsigned)((thr + 255) / 256)), 256, 0, stream>>>(
        q, k, v, qrb, krb, vrb, inmap);
  }
  {
    long thr = 2L * NH * NS * 8;
    k_sample<<<dim3((unsigned)((thr + 255) / 256)), 256, 0, stream>>>(
        q, k, sqh, sqm, sql, skh, skm, skl, qidx, kidx, inmap);
  }
  k_scores_pool<<<dim3(NH * NBLK), 256, 0, stream>>>(
      sqh, sqm, sql, skh, skm, skl, pool);
  k_mask<<<dim3(NH * NBLK), 192, 0, stream>>>(pool, dmask);
  {
    long rows = 2L * NH * NBLK * 112;
    k_poolkv<<<dim3((unsigned)((rows + 3) / 4)), 256, 0, stream>>>(krb, vrb, Kpb, Vpb);
  }
  {
    long thr = (long)NGALL * 128;
    k_fragk<<<dim3((unsigned)((thr + 255) / 256)), 256, 0, stream>>>(krb, Kpb, kfAll);
  }
  {
    long thr = (long)NGALL * 256;
    k_fragv<<<dim3((unsigned)((thr + 255) / 256)), 256, 0, stream>>>(vrb, Vpb, vfAll);
  }
  k_attn_heavy<<<dim3(NHEAVYB), 256, 0, stream>>>(qrb, krb, vrb, part, plsum);
  k_attn_light<<<dim3(NLIGHT2), 256, 0, stream>>>(qrb, kfAll, vfAll, dmask, dstrow, out);
  k_combine<<<dim3(NH * 2), 256, 0, stream>>>(part, plsum, dstrow, out);
  if (ndup > 0) {
    k_fixup<<<dim3((unsigned)(ndup * NH)), 64, 0, stream>>>(duppairs, out, ndup);
  }
}

// Round 16
// 484.426 us; speedup vs baseline: 1.0183x; 1.0183x over previous
//
#include <hip/hip_runtime.h>
#include <stdint.h>
#include <string.h>
#include <stdlib.h>

#define JAX_PARTITIONABLE 1

namespace {

constexpr int kW = 45, kH = 30, kD = 13;
constexpr int NVID = kW * kH * kD;          // 17550
constexpr int TEXT = 226;
constexpr int LSEQ = TEXT + NVID;           // 17776
constexpr int BLKSZ = 128;
constexpr int NBLK = 139;
constexpr int LPAD = NBLK * BLKSZ;          // 17792
constexpr int NKEEP = 32;
constexpr int NS = NBLK * NKEEP;            // 4448
constexpr int NH = 8;
constexpr int DD = 64;
constexpr int VLAST = LSEQ - (NBLK - 1) * BLKSZ;  // 112
constexpr float SCALE = 0.125f;
constexpr float SC2 = 0.18033688011120542f;  // SCALE * log2(e)
constexpr int MAXG = 188;

// group spaces (16-row groups)
constexpr int NGR_H = LPAD / 16;            // 1112 raw groups per head
constexpr int NRAWG = NH * NGR_H;           // 8896
constexpr int NPOOLG = NH * NBLK * 7;       // 7784
constexpr int NGALL = NRAWG + NPOOLG;       // 16680

// heavy split
constexpr int NSPLIT = 16;
constexpr int HCHUNK = (LSEQ + 63) / 64;    // 278
constexpr int CHPER = (HCHUNK + NSPLIT - 1) / NSPLIT;
constexpr int NHEAVYB = NH * 2 * NSPLIT;
constexpr int NLIGHT2 = NH * (NBLK - 2) * 2;  // 2192 (64 q-rows per block)

// ---------------- workspace layout (float units) ----------------
constexpr long SZ_RB = (long)NH * LPAD * DD / 2;    // bf16 arrays
constexpr long SZ_SH = (long)NH * NS * DD / 2;
constexpr long SZ_KPB = (long)NH * NBLK * 112 * DD / 2;
constexpr long SZ_KF = (long)NGALL * 1024 / 2;
constexpr long SZ_VF = (long)NGALL * 1024 / 2;
constexpr long SZ_PL = (long)NH * NBLK * NBLK;
constexpr long SZ_PT = (long)NH * 2 * NSPLIT * BLKSZ * DD;
constexpr long SZ_PS = (long)NH * 2 * NSPLIT * BLKSZ;
constexpr long F_QB = 0;
constexpr long F_KB = F_QB + SZ_RB;
constexpr long F_VB = F_KB + SZ_RB;
constexpr long F_SQH = F_VB + SZ_RB;
constexpr long F_SQM = F_SQH + SZ_SH;
constexpr long F_SQL = F_SQM + SZ_SH;
constexpr long F_SKH = F_SQL + SZ_SH;
constexpr long F_SKM = F_SKH + SZ_SH;
constexpr long F_SKL = F_SKM + SZ_SH;
constexpr long F_KPB = F_SKL + SZ_SH;
constexpr long F_VPB = F_KPB + SZ_KPB;
constexpr long F_KFA = F_VPB + SZ_KPB;
constexpr long F_VFA = F_KFA + SZ_KF;
constexpr long F_PL = F_VFA + SZ_VF;
constexpr long F_MK = F_PL + SZ_PL;                 // int32
constexpr long F_PT = F_MK + SZ_PL;
constexpr long F_PS = F_PT + SZ_PT;
constexpr long F_TB = F_PS + SZ_PS;                 // int32 tables
constexpr int TAB_MAX = 2 * LSEQ + 2 * NH * NKEEP + 2 * NVID;

// ============================ host: gilbert =============================
// Faithful port of the PROBLEM's _gen3d (volume-deficient regular-else branch
// included). o2g keeps trailing zeros; g2o keeps zeros for missed cells.
struct Gil { int* out; int n; };
static inline int sgn_i(int v) { return (v > 0) - (v < 0); }
static inline int fd2(int a) { return a >= 0 ? a / 2 : -((-a + 1) / 2); }

static void gen3d(Gil& G, int x, int y, int z,
                  int ax, int ay, int az,
                  int bx, int by, int bz,
                  int cx, int cy, int cz) {
  int w = abs(ax + ay + az), h = abs(bx + by + bz), d = abs(cx + cy + cz);
  int dax = sgn_i(ax), day = sgn_i(ay), daz = sgn_i(az);
  int dbx = sgn_i(bx), dby = sgn_i(by), dbz = sgn_i(bz);
  int dcx = sgn_i(cx), dcy = sgn_i(cy), dcz = sgn_i(cz);
  if (h == 1 && d == 1) { for (int i = 0; i < w; i++) { G.out[G.n++] = x + kW * (y + kH * z); x += dax; y += day; z += daz; } return; }
  if (w == 1 && d == 1) { for (int i = 0; i < h; i++) { G.out[G.n++] = x + kW * (y + kH * z); x += dbx; y += dby; z += dbz; } return; }
  if (w == 1 && h == 1) { for (int i = 0; i < d; i++) { G.out[G.n++] = x + kW * (y + kH * z); x += dcx; y += dcy; z += dcz; } return; }
  int ax2 = fd2(ax), ay2 = fd2(ay), az2 = fd2(az);
  int bx2 = fd2(bx), by2 = fd2(by), bz2 = fd2(bz);
  int cx2 = fd2(cx), cy2 = fd2(cy), cz2 = fd2(cz);
  int w2 = abs(ax2 + ay2 + az2), h2 = abs(bx2 + by2 + bz2), d2 = abs(cx2 + cy2 + cz2);
  if ((w2 & 1) && w > 2) { ax2 += dax; ay2 += day; az2 += daz; }
  if ((h2 & 1) && h > 2) { bx2 += dbx; by2 += dby; bz2 += dbz; }
  if ((d2 & 1) && d > 2) { cx2 += dcx; cy2 += dcy; cz2 += dcz; }
  if (2 * w > 3 * h && 2 * w > 3 * d) {
    gen3d(G, x, y, z, ax2, ay2, az2, bx, by, bz, cx, cy, cz);
    gen3d(G, x + ax2, y + ay2, z + az2, ax - ax2, ay - ay2, az - az2, bx, by, bz, cx, cy, cz);
  } else if (3 * h > 4 * d) {
    gen3d(G, x, y, z, bx2, by2, bz2, cx, cy, cz, ax2, ay2, az2);
    gen3d(G, x + bx2, y + by2, z + bz2, ax, ay, az, bx - bx2, by - by2, bz - bz2, cx, cy, cz);
    gen3d(G, x + (ax - dax) + (bx2 - dbx), y + (ay - day) + (by2 - dby), z + (az - daz) + (bz2 - dbz),
          -bx2, -by2, -bz2, cx, cy, cz, -(ax - ax2), -(ay - ay2), -(az - az2));
  } else if (3 * d > 4 * h) {
    gen3d(G, x, y, z, cx2, cy2, cz2, ax2, ay2, az2, bx, by, bz);
    gen3d(G, x + cx2, y + cy2, z + cz2, ax, ay, az, bx, by, bz, cx - cx2, cy - cy2, cz - cz2);
    gen3d(G, x + (ax - dax) + (cx2 - dcx), y + (ay - day) + (cy2 - dcy), z + (az - daz) + (cz2 - dcz),
          -cx2, -cy2, -cz2, -(ax - ax2), -(ay - ay2), -(az - az2), bx, by, bz);
  } else {
    gen3d(G, x, y, z, bx2, by2, bz2, cx2, cy2, cz2, ax2, ay2, az2);
    gen3d(G, x + bx2, y + by2, z + bz2, cx, cy, cz, ax2, ay2, az2, bx - bx2, by - by2, bz - bz2);
    gen3d(G, x + (bx2 - dbx) + (cx - dcx), y + (by2 - dby) + (cy - dcy), z + (bz2 - dbz) + (cz - dcz),
          ax, ay, az, -bx2, -by2, -bz2, -(cx - cx2), -(cy - cy2), -(cz - cz2));
    gen3d(G, x + (ax - dax) + bx2 + (cx - dcx), y + (ay - day) + by2 + (cy - dcy), z + (az - daz) + bz2 + (cz - dcz),
          -cx, -cy, -cz, -(ax - ax2), -(ay - ay2), -(az - az2), bx - bx2, by - by2, bz - bz2);
  }
}

// ============================ host: threefry ============================
static void tf2x32(uint32_t k0, uint32_t k1, uint32_t x0, uint32_t x1,
                   uint32_t& o0, uint32_t& o1) {
  uint32_t ks0 = k0, ks1 = k1, ks2 = k0 ^ k1 ^ 0x1BD11BDAu;
  const uint32_t ks[3] = {ks0, ks1, ks2};
  const int rot[2][4] = {{13, 15, 26, 6}, {17, 29, 16, 24}};
  x0 += ks[0]; x1 += ks[1];
  for (int i = 0; i < 5; i++) {
    for (int j = 0; j < 4; j++) {
      int rr = rot[i & 1][j];
      x0 += x1;
      x1 = (x1 << rr) | (x1 >> (32 - rr));
      x1 ^= x0;
    }
    x0 += ks[(i + 1) % 3];
    x1 += ks[(i + 2) % 3] + (uint32_t)(i + 1);
  }
  o0 = x0; o1 = x1;
}

static inline float bits_to_unit(uint32_t bits) {
  uint32_t fb = (bits >> 9) | 0x3f800000u;
  float f; memcpy(&f, &fb, 4);
  return f - 1.0f;
}

static void fill_idx(uint32_t K0, uint32_t K1, int* dst) {
  float u[NH * BLKSZ];
#if JAX_PARTITIONABLE
  for (int i = 0; i < NH * BLKSZ; i++) {
    uint32_t a, b; tf2x32(K0, K1, 0u, (uint32_t)i, a, b);
    u[i] = bits_to_unit(a ^ b);
  }
#else
  {
    const int n = NH * BLKSZ, hn = n / 2;
    for (int i = 0; i < hn; i++) {
      uint32_t a, b; tf2x32(K0, K1, (uint32_t)i, (uint32_t)(hn + i), a, b);
      u[i] = bits_to_unit(a);
      u[hn + i] = bits_to_unit(b);
    }
  }
#endif
  for (int h = 0; h < NH; h++) {
    const float* row = u + h * BLKSZ;
    bool used[BLKSZ] = {false};
    for (int r = 0; r < NKEEP; r++) {
      int best = -1; float bv = -2.0f;
      for (int g = 0; g < BLKSZ; g++)
        if (!used[g] && row[g] > bv) { bv = row[g]; best = g; }
      used[best] = true;
      dst[h * NKEEP + r] = best;
    }
  }
}

static int g_ndup = 0;

static void build_tables(int* tab) {
  static int yields[NVID];
  static int o2g_buf[NVID];
  static int g2o_buf[NVID];
  static int outg_loc[LSEQ];
  memset(o2g_buf, 0, sizeof(o2g_buf));
  memset(g2o_buf, 0, sizeof(g2o_buf));
  Gil G{yields, 0};
  gen3d(G, 0, 0, 0, kW, 0, 0, 0, kH, 0, 0, 0, kD);
  int n = G.n;
  if (n > NVID) n = NVID;
  for (int g = 0; g < n; g++) o2g_buf[g] = yields[g];
  for (int g = 0; g < n; g++) g2o_buf[yields[g]] = g;

  int* inmap = tab;                         // [LSEQ]
  int* dstrow = tab + LSEQ;                 // [LSEQ]
  int* qidx = tab + 2 * LSEQ;               // [NH*NKEEP]
  int* kidx = qidx + NH * NKEEP;            // [NH*NKEEP]
  int* duppairs = kidx + NH * NKEEP;        // [2*ndup]

  for (int g = 0; g < NVID; g++) inmap[g] = TEXT + o2g_buf[g];
  for (int t = 0; t < TEXT; t++) inmap[NVID + t] = t;
  for (int r = 0; r < TEXT; r++) outg_loc[r] = NVID + r;
  for (int c = 0; c < NVID; c++) outg_loc[TEXT + c] = g2o_buf[c];

  for (int g = 0; g < LSEQ; g++) dstrow[g] = -1;
  int nd = 0;
  for (int r = 0; r < LSEQ; r++) {
    int g = outg_loc[r];
    if (dstrow[g] < 0) dstrow[g] = r;
    else { duppairs[2 * nd] = r; duppairs[2 * nd + 1] = dstrow[g]; nd++; }
  }
  g_ndup = nd;

  uint32_t kq0, kq1, kk0, kk1;
#if JAX_PARTITIONABLE
  tf2x32(0, 0, 0, 0, kq0, kq1);
  tf2x32(0, 0, 0, 1, kk0, kk1);
#else
  {
    uint32_t y00, y10, y01, y11;
    tf2x32(0, 0, 0, 2, y00, y10);
    tf2x32(0, 0, 1, 3, y01, y11);
    kq0 = y00; kq1 = y01; kk0 = y10; kk1 = y11;
  }
#endif
  fill_idx(kq0, kq1, qidx);
  fill_idx(kk0, kk1, kidx);
}

}  // namespace

// ============================ device helpers ============================

typedef __attribute__((ext_vector_type(8))) short short8v;
typedef __attribute__((ext_vector_type(4))) float f32x4;

static __device__ inline unsigned short f2bf(float f) {
  unsigned u = __float_as_uint(f);
  unsigned r = u + 0x7FFFu + ((u >> 16) & 1u);  // RNE
  return (unsigned short)(r >> 16);
}
static __device__ inline float bf2f(unsigned short s) {
  return __uint_as_float(((unsigned)s) << 16);
}
static __device__ inline int cvtpk(float lo, float hi) {
  int r;
  asm("v_cvt_pk_bf16_f32 %0, %1, %2" : "=v"(r) : "v"(lo), "v"(hi));
  return r;
}

struct KFrag {
  short8v h[2][2], m[2][2], l[2][2];
};

// ============================ device kernels ============================

// rearrange -> bf16 row-major arrays (b128 writes)
__global__ __launch_bounds__(256) void k_rearr(
    const float* __restrict__ q, const float* __restrict__ k, const float* __restrict__ v,
    short* __restrict__ qrb, short* __restrict__ krb, short* __restrict__ vrb,
    const int* __restrict__ inmap) {
  long gid = (long)blockIdx.x * 256 + threadIdx.x;
  const long totalRows = 3L * NH * LPAD;
  long rowid = gid >> 3;
  int g8 = (int)(gid & 7);
  if (rowid >= totalRows) return;
  int tsel = (int)(rowid / ((long)NH * LPAD));
  long rem = rowid - (long)tsel * NH * LPAD;
  int h = (int)(rem / LPAD);
  int i = (int)(rem % LPAD);
  const float* src = tsel == 0 ? q : (tsel == 1 ? k : v);
  short8v outv;
  if (i < LSEQ) {
    const float* sp = src + ((long)h * LSEQ + inmap[i]) * DD + g8 * 8;
    float4 a = *(const float4*)sp;
    float4 b = *(const float4*)(sp + 4);
    float vals[8] = {a.x, a.y, a.z, a.w, b.x, b.y, b.z, b.w};
#pragma unroll
    for (int j = 0; j < 8; j++) outv[j] = (short)f2bf(vals[j]);
  } else {
#pragma unroll
    for (int j = 0; j < 8; j++) outv[j] = 0;
  }
  short* dst = tsel == 0 ? qrb : (tsel == 1 ? krb : vrb);
  *(short8v*)(dst + ((long)h * LPAD + i) * DD + g8 * 8) = outv;
}

// sampled q/k rows -> fragment-major 3-way bf16 split arrays
__global__ __launch_bounds__(256) void k_sample(
    const float* __restrict__ q, const float* __restrict__ k,
    short* __restrict__ sqh, short* __restrict__ sqm, short* __restrict__ sql,
    short* __restrict__ skh, short* __restrict__ skm, short* __restrict__ skl,
    const int* __restrict__ qidx, const int* __restrict__ kidx,
    const int* __restrict__ inmap) {
  long gid = (long)blockIdx.x * 256 + threadIdx.x;
  int g = (int)(gid & 7);
  long rowid = gid >> 3;
  const long half = (long)NH * NS;
  if (rowid >= 2 * half) return;
  int tsel = rowid >= half;
  long rem = tsel ? rowid - half : rowid;
  int h = (int)(rem / NS);
  int s = (int)(rem % NS);
  int b = s / NKEEP, t = s % NKEEP;
  const int* idx = tsel ? kidx : qidx;
  int p = b * BLKSZ + idx[h * NKEEP + t];
  if (p >= LSEQ) p = LSEQ - 1;
  int orig = inmap[p];
  const float* src = (tsel ? k : q) + ((long)h * LSEQ + orig) * DD + g * 8;
  float4 a = *(const float4*)src;
  float4 bb = *(const float4*)(src + 4);
  float vals[8] = {a.x, a.y, a.z, a.w, bb.x, bb.y, bb.z, bb.w};
  short8v vh, vm, vl;
#pragma unroll
  for (int j = 0; j < 8; j++) {
    unsigned short hi = f2bf(vals[j]);
    float r1 = vals[j] - bf2f(hi);
    unsigned short mi = f2bf(r1);
    float r2 = r1 - bf2f(mi);
    unsigned short lo = f2bf(r2);
    vh[j] = (short)hi; vm[j] = (short)mi; vl[j] = (short)lo;
  }
  int t16 = s >> 4, lm = s & 15, ks = g >> 2, lg = g & 3;
  long off = (long)h * NS * DD + ((long)(t16 * 2 + ks)) * 512 + (lg * 16 + lm) * 8;
  if (tsel) {
    *(short8v*)(skh + off) = vh;
    *(short8v*)(skm + off) = vm;
    *(short8v*)(skl + off) = vl;
  } else {
    *(short8v*)(sqh + off) = vh;
    *(short8v*)(sqm + off) = vm;
    *(short8v*)(sql + off) = vl;
  }
}

static __device__ inline void ld_frags(
    const short* __restrict__ skh, const short* __restrict__ skm,
    const short* __restrict__ skl, long kbase, int c, int lane, KFrag& F) {
#pragma unroll
  for (int nt = 0; nt < 2; nt++)
#pragma unroll
    for (int ks = 0; ks < 2; ks++) {
      long a = kbase + ((long)((2 * c + nt) * 2 + ks)) * 512 + lane * 8;
      F.h[nt][ks] = *(const short8v*)(skh + a);
      F.m[nt][ks] = *(const short8v*)(skm + a);
      F.l[nt][ks] = *(const short8v*)(skl + a);
    }
}

// scores+pool: fragment-direct, split-bf16 6-term MFMA. bid&7 = head.
__global__ __launch_bounds__(256, 2) void k_scores_pool(
    const short* __restrict__ sqh, const short* __restrict__ sqm, const short* __restrict__ sql,
    const short* __restrict__ skh, const short* __restrict__ skm, const short* __restrict__ skl,
    float* __restrict__ pool) {
  __shared__ float bins[32][145];
  __shared__ float invden[32];
  int bid = blockIdx.x;
  int h = bid & 7, qb = bid >> 3;
  int tid = threadIdx.x;
  int wid = tid >> 6, lane = tid & 63;
  int lm = lane & 15, lg = lane >> 4;

  for (int i = tid; i < 32 * 145; i += 256) (&bins[0][0])[i] = 0.f;

  const long base = (long)h * NS * DD;
  short8v Qh[2][2], Qm[2][2], Ql[2][2];
#pragma unroll
  for (int mt = 0; mt < 2; mt++)
#pragma unroll
    for (int ks = 0; ks < 2; ks++) {
      long off = base + ((long)((2 * qb + mt) * 2 + ks)) * 512 + lane * 8;
      Qh[mt][ks] = *(const short8v*)(sqh + off);
      Qm[mt][ks] = *(const short8v*)(sqm + off);
      Ql[mt][ks] = *(const short8v*)(sql + off);
    }
  __syncthreads();

  auto compute = [&](const KFrag& F, int c) {
    f32x4 aq[2][2];
#pragma unroll
    for (int mt = 0; mt < 2; mt++)
#pragma unroll
      for (int nt = 0; nt < 2; nt++) {
        f32x4 a = {0.f, 0.f, 0.f, 0.f};
#pragma unroll
        for (int ks = 0; ks < 2; ks++) {
          a = __builtin_amdgcn_mfma_f32_16x16x32_bf16(F.h[nt][ks], Qh[mt][ks], a, 0, 0, 0);
          a = __builtin_amdgcn_mfma_f32_16x16x32_bf16(F.h[nt][ks], Qm[mt][ks], a, 0, 0, 0);
          a = __builtin_amdgcn_mfma_f32_16x16x32_bf16(F.m[nt][ks], Qh[mt][ks], a, 0, 0, 0);
          a = __builtin_amdgcn_mfma_f32_16x16x32_bf16(F.m[nt][ks], Qm[mt][ks], a, 0, 0, 0);
          a = __builtin_amdgcn_mfma_f32_16x16x32_bf16(F.h[nt][ks], Ql[mt][ks], a, 0, 0, 0);
          a = __builtin_amdgcn_mfma_f32_16x16x32_bf16(F.l[nt][ks], Qh[mt][ks], a, 0, 0, 0);
        }
        aq[mt][nt] = a;
      }
#pragma unroll
    for (int mt = 0; mt < 2; mt++) {
      float s = 0.f;
#pragma unroll
      for (int nt = 0; nt < 2; nt++)
#pragma unroll
        for (int i = 0; i < 4; i++)
          s += __expf(aq[mt][nt][i] * SCALE);
      s += __shfl_xor(s, 16);
      s += __shfl_xor(s, 32);
      if (lg == 0) bins[mt * 16 + lm][c] += s;
    }
  };

  KFrag A, B;
  ld_frags(skh, skm, skl, base, wid, lane, A);
  for (int c = wid; c < NBLK; c += 8) {
    if (c + 4 < NBLK) ld_frags(skh, skm, skl, base, c + 4, lane, B);
    compute(A, c);
    if (c + 4 >= NBLK) break;
    if (c + 8 < NBLK) ld_frags(skh, skm, skl, base, c + 8, lane, A);
    compute(B, c + 4);
  }

  __syncthreads();
  if (tid < 32) {
    float s = 0.f;
    for (int kb = 0; kb < NBLK; kb++) s += bins[tid][kb];
    invden[tid] = 1.0f / s;
  }
  __syncthreads();
  if (tid < NBLK) {
    float s = 0.f;
    for (int r2 = 0; r2 < NKEEP; r2++) s += bins[r2][tid] * invden[r2];
    pool[((long)h * NBLK + qb) * NBLK + tid] = s;
  }
}

__global__ __launch_bounds__(192) void k_mask(
    const float* __restrict__ pool, int* __restrict__ mask) {
  __shared__ float row[NBLK];
  int h = blockIdx.x / NBLK, i = blockIdx.x % NBLK;
  int t = threadIdx.x;
  const float* pr = pool + ((long)h * NBLK + i) * NBLK;
  if (t < NBLK) row[t] = pr[t];
  __syncthreads();
  if (t < NBLK) {
    float pv = row[t];
    int rank = 0;
    for (int j = 0; j < NBLK; j++) {
      float o = row[j];
      rank += (o > pv) || (o == pv && j < t);
    }
    int val = 0;
    if (rank < 6) val = 1;
    else if (rank < 20) val = 2;
    else if (rank < 34) val = 4;
    else if (rank < 69) val = 8;
    if (t >= NBLK - 2) val = 1;
    if (i >= NBLK - 2) val = 1;
    mask[((long)h * NBLK + i) * NBLK + t] = val;
  }
}

__global__ __launch_bounds__(256) void k_poolkv(
    const short* __restrict__ krb, const short* __restrict__ vrb,
    short* __restrict__ Kpb, short* __restrict__ Vpb) {
  long rid = (long)blockIdx.x * 4 + (threadIdx.x >> 6);
  int d = threadIdx.x & 63;
  const long total = 2L * NH * NBLK * 112;
  if (rid >= total) return;
  int tsel = (int)(rid / ((long)NH * NBLK * 112));
  long rem = rid - (long)tsel * NH * NBLK * 112;
  int h = (int)(rem / (NBLK * 112));
  int rem2 = (int)(rem % (NBLK * 112));
  int j = rem2 / 112, p = rem2 % 112;
  int m, g;
  if (p < 64) { m = 2; g = p; }
  else if (p < 96) { m = 4; g = p - 64; }
  else { m = 8; g = p - 96; }
  const short* src = tsel ? vrb : krb;
  const short* base = src + ((long)h * LPAD + j * BLKSZ + g * m) * DD + d;
  float sum = 0.f;
  for (int r2 = 0; r2 < m; r2++) sum += bf2f((unsigned short)base[(long)r2 * DD]);
  short* dst = tsel ? Vpb : Kpb;
  dst[(((long)h * NBLK + j) * 112 + p) * DD + d] = (short)f2bf(sum / (float)m);
}

// fragment-major K builder
__global__ __launch_bounds__(256) void k_fragk(
    const short* __restrict__ krb, const short* __restrict__ Kpb,
    short* __restrict__ kfAll) {
  long gid = (long)blockIdx.x * 256 + threadIdx.x;
  if (gid >= (long)NGALL * 128) return;
  int lane = (int)(gid & 63);
  int ks = (int)((gid >> 6) & 1);
  long grp = gid >> 7;
  int lm = lane & 15, lg = lane >> 4;
  const short* srcp;
  long row;
  if (grp < NRAWG) { srcp = krb; row = grp * 16 + lm; }
  else { srcp = Kpb; row = (grp - NRAWG) * 16 + lm; }
  short8v vv = *(const short8v*)(srcp + row * DD + ks * 32 + lg * 8);
  *(short8v*)(kfAll + ((long)grp * 2 + ks) * 512 + lane * 8) = vv;
}

// fragment-major V^T builder
__global__ __launch_bounds__(256) void k_fragv(
    const short* __restrict__ vrb, const short* __restrict__ Vpb,
    short* __restrict__ vfAll) {
  long gid = (long)blockIdx.x * 256 + threadIdx.x;
  if (gid >= (long)NGALL * 256) return;
  int lane = (int)(gid & 63);
  int mtp = (int)((gid >> 6) & 3);
  long grp = gid >> 8;
  int lm = lane & 15, lg = lane >> 4;
  const short* srcp;
  long rowb;
  if (grp < NRAWG) { srcp = vrb; rowb = grp * 16 + lg * 4; }
  else { srcp = Vpb; rowb = (grp - NRAWG) * 16 + lg * 4; }
  short4 o;
  o.x = srcp[(rowb + 0) * DD + mtp * 16 + lm];
  o.y = srcp[(rowb + 1) * DD + mtp * 16 + lm];
  o.z = srcp[(rowb + 2) * DD + mtp * 16 + lm];
  o.w = srcp[(rowb + 3) * DD + mtp * 16 + lm];
  *(short4*)(vfAll + ((long)grp * 4 + mtp) * 256 + lane * 4) = o;
}

// ---------- LIGHT attention: 64 q-rows/block, single-buffer staging ----------
// (round-14 inner loop: 2 barriers/chunk, paired-V layout, ones-MFMA denom)
// + direct-scatter output via dstrow.
__global__ __launch_bounds__(256, 2) void k_attn_light(
    const short* __restrict__ qrb,
    const short* __restrict__ kfAll, const short* __restrict__ vfAll,
    const int* __restrict__ mask, const int* __restrict__ dstrow,
    float* __restrict__ out) {
  __shared__ int glist[MAXG];
  __shared__ int wtot[4];
  __shared__ int smeta;
  __shared__ __align__(16) short KtF[4096];
  __shared__ __align__(16) short VtF[4096];

  int bid = blockIdx.x;
  int half = bid & 1;
  int lb = bid >> 1;
  int h = lb / (NBLK - 2);
  int qi = lb % (NBLK - 2);
  int tid = threadIdx.x;
  int lane = tid & 63, wid = tid >> 6;
  int lm = lane & 15, lg = lane >> 4;

  // per-column group counts + shfl scan
  int myng = 0, mylvl = 0, myG = 0;
  if (tid < NBLK) {
    int mv = mask[((long)h * NBLK + qi) * NBLK + tid];
    if (mv) {
      mylvl = (mv == 1) ? 0 : (mv == 2) ? 1 : (mv == 4) ? 2 : 3;
      myG = ((tid == NBLK - 1) ? VLAST : BLKSZ) >> mylvl;
      myng = (myG + 15) >> 4;
    }
  }
  int v = myng;
#pragma unroll
  for (int off = 1; off < 64; off <<= 1) {
    int t2 = __shfl_up(v, off);
    if ((tid & 63) >= off) v += t2;
  }
  if ((tid & 63) == 63) wtot[wid] = v;
  __syncthreads();
  int woff = 0;
#pragma unroll
  for (int w = 0; w < 4; w++) if (w < wid) woff += wtot[w];
  int myoff = woff + v - myng;
  if (tid == 0) {
    int tot = wtot[0] + wtot[1] + wtot[2] + wtot[3];
    while (tot & 3) glist[tot++] = 0;
    smeta = tot >> 2;
  }
  __syncthreads();
  if (tid < NBLK && myng) {
    int grp0;
    if (mylvl == 0) grp0 = h * NGR_H + tid * 8;
    else {
      int l16 = (mylvl == 1) ? 0 : (mylvl == 2) ? 4 : 6;
      grp0 = NRAWG + (h * NBLK + tid) * 7 + l16;
    }
    for (int g = 0; g < myng; g++) {
      int cnt = myG - 16 * g; if (cnt > 16) cnt = 16;
      glist[myoff + g] = (grp0 + g) | (cnt << 24) | (mylvl << 29);
    }
  }
  __syncthreads();
  int nchunks = smeta;

  // Q fragments (16 rows per wave)
  short8v Qf[2];
  {
    long row = (long)h * LPAD + qi * BLKSZ + half * 64 + wid * 16 + lm;
    Qf[0] = *(const short8v*)(qrb + row * DD + lg * 8);
    Qf[1] = *(const short8v*)(qrb + row * DD + 32 + lg * 8);
  }
  short8v onesv;
#pragma unroll
  for (int j = 0; j < 8; j++) onesv[j] = (short)0x3F80;  // bf16 1.0
  f32x4 Oacc[4];
#pragma unroll
  for (int a = 0; a < 4; a++) { f32x4 z = {0.f, 0.f, 0.f, 0.f}; Oacc[a] = z; }
  f32x4 Oden = {0.f, 0.f, 0.f, 0.f};

  // staging regs
  short8v rk0, rk1, rv0, rv1;
  auto ldStage = [&](int c) {
    {
      int s = tid;
      long grp = (long)((unsigned)glist[4 * c + (s >> 7)] & 0xFFFFFFu);
      rk0 = *(const short8v*)(kfAll + (grp * 2 + ((s >> 6) & 1)) * 512 + (long)(s & 63) * 8);
      s = tid + 256;
      grp = (long)((unsigned)glist[4 * c + (s >> 7)] & 0xFFFFFFu);
      rk1 = *(const short8v*)(kfAll + (grp * 2 + ((s >> 6) & 1)) * 512 + (long)(s & 63) * 8);
    }
    {
      int s = tid;
      long grp = (long)((unsigned)glist[4 * c + (s >> 7)] & 0xFFFFFFu);
      rv0 = *(const short8v*)(vfAll + (grp * 4 + ((s >> 5) & 3)) * 256 + (long)(s & 31) * 8);
      s = tid + 256;
      grp = (long)((unsigned)glist[4 * c + (s >> 7)] & 0xFFFFFFu);
      rv1 = *(const short8v*)(vfAll + (grp * 4 + ((s >> 5) & 3)) * 256 + (long)(s & 31) * 8);
    }
  };
  auto stStage = [&]() {
    *(short8v*)&KtF[tid * 8] = rk0;
    *(short8v*)&KtF[(tid + 256) * 8] = rk1;
    {
      int s = tid;
      int g = s >> 7, mtp = (s >> 5) & 3, l = s & 31;
      int base = (mtp * 2 + (g >> 1)) * 512 + ((g & 1) * 4) + l * 16;
      *(short4*)&VtF[base] = make_short4(rv0[0], rv0[1], rv0[2], rv0[3]);
      *(short4*)&VtF[base + 8] = make_short4(rv0[4], rv0[5], rv0[6], rv0[7]);
      s = tid + 256;
      g = s >> 7; mtp = (s >> 5) & 3; l = s & 31;
      base = (mtp * 2 + (g >> 1)) * 512 + ((g & 1) * 4) + l * 16;
      *(short4*)&VtF[base] = make_short4(rv1[0], rv1[1], rv1[2], rv1[3]);
      *(short4*)&VtF[base + 8] = make_short4(rv1[4], rv1[5], rv1[6], rv1[7]);
    }
  };

  ldStage(0);
  for (int c = 0; c < nchunks; c++) {
    __syncthreads();   // previous chunk's LDS reads complete
    stStage();
    __syncthreads();
    if (c + 1 < nchunks) ldStage(c + 1);

    int cntv[4]; float biasv[4];
#pragma unroll
    for (int g = 0; g < 4; g++) {
      unsigned e = (unsigned)glist[4 * c + g];
      cntv[g] = (e >> 24) & 31;
      biasv[g] = (float)((e >> 29) & 3);   // exp2-domain bias = lvl
    }
    bool allfull = (cntv[0] == 16) & (cntv[1] == 16) & (cntv[2] == 16) & (cntv[3] == 16);

    // QK^T
    f32x4 aq[4];
#pragma unroll
    for (int nt = 0; nt < 4; nt++) {
      short8v k0 = *(short8v*)&KtF[(nt * 2 + 0) * 512 + lane * 8];
      short8v k1 = *(short8v*)&KtF[(nt * 2 + 1) * 512 + lane * 8];
      f32x4 z = {0.f, 0.f, 0.f, 0.f};
      f32x4 a = __builtin_amdgcn_mfma_f32_16x16x32_bf16(k0, Qf[0], z, 0, 0, 0);
      aq[nt] = __builtin_amdgcn_mfma_f32_16x16x32_bf16(k1, Qf[1], a, 0, 0, 0);
    }
    // softmax
    float ps[16];
    if (allfull) {
#pragma unroll
      for (int nt = 0; nt < 4; nt++)
#pragma unroll
        for (int i = 0; i < 4; i++)
          ps[nt * 4 + i] = exp2f(fmaf(aq[nt][i], SC2, biasv[nt]));
    } else {
#pragma unroll
      for (int nt = 0; nt < 4; nt++)
#pragma unroll
        for (int i = 0; i < 4; i++) {
          int kvr = lg * 4 + i;
          ps[nt * 4 + i] = (kvr < cntv[nt]) ? exp2f(fmaf(aq[nt][i], SC2, biasv[nt])) : 0.f;
        }
    }
    short8v Pf[2];
#pragma unroll
    for (int H = 0; H < 2; H++) {
      union { int i[4]; short8v v; } u;
      u.i[0] = cvtpk(ps[8 * H + 0], ps[8 * H + 1]);
      u.i[1] = cvtpk(ps[8 * H + 2], ps[8 * H + 3]);
      u.i[2] = cvtpk(ps[8 * H + 4], ps[8 * H + 5]);
      u.i[3] = cvtpk(ps[8 * H + 6], ps[8 * H + 7]);
      Pf[H] = u.v;
    }
    // denominator on the MFMA pipe (ones-column trick)
    Oden = __builtin_amdgcn_mfma_f32_16x16x32_bf16(onesv, Pf[0], Oden, 0, 0, 0);
    Oden = __builtin_amdgcn_mfma_f32_16x16x32_bf16(onesv, Pf[1], Oden, 0, 0, 0);
    // PV (paired layout: b128 reads)
#pragma unroll
    for (int mtp = 0; mtp < 4; mtp++) {
      short8v vf0 = *(short8v*)&VtF[(mtp * 2 + 0) * 512 + lane * 8];
      short8v vf1 = *(short8v*)&VtF[(mtp * 2 + 1) * 512 + lane * 8];
      Oacc[mtp] = __builtin_amdgcn_mfma_f32_16x16x32_bf16(vf0, Pf[0], Oacc[mtp], 0, 0, 0);
      Oacc[mtp] = __builtin_amdgcn_mfma_f32_16x16x32_bf16(vf1, Pf[1], Oacc[mtp], 0, 0, 0);
    }
  }

  float inv = 1.0f / Oden[0];
  {
    int grow = qi * BLKSZ + half * 64 + wid * 16 + lm;
    int dr = dstrow[grow];
    if (dr >= 0) {
      float* orow = out + ((long)h * LSEQ + dr) * DD;
#pragma unroll
      for (int mtp = 0; mtp < 4; mtp++) {
        f32x4 o = Oacc[mtp];
        *(float4*)(orow + mtp * 16 + lg * 4) =
            make_float4(o[0] * inv, o[1] * inv, o[2] * inv, o[3] * inv);
      }
    }
  }
}

// ---------------- HEAVY (full-attn) q-blocks ----------------
__global__ __launch_bounds__(256, 1) void k_attn_heavy(
    const short* __restrict__ qrb, const short* __restrict__ krb,
    const short* __restrict__ vrb,
    float* __restrict__ part, float* __restrict__ plsum) {
  __shared__ __align__(16) short Kt[64 * 64];
  __shared__ __align__(16) short Vt[64 * 68];

  int bid = blockIdx.x;
  int split = bid & (NSPLIT - 1);
  int hq = bid / NSPLIT;
  int h = hq >> 1;
  int qi = NBLK - 2 + (hq & 1);
  int c0 = split * CHPER;
  int c1 = c0 + CHPER; if (c1 > HCHUNK) c1 = HCHUNK;
  int slot = hq * NSPLIT + split;
  int tid = threadIdx.x;

  int lane = tid & 63, wid = tid >> 6;
  int lm = lane & 15, lg = lane >> 4;

  short8v Qf[2][2];
#pragma unroll
  for (int mt = 0; mt < 2; mt++)
#pragma unroll
    for (int ks = 0; ks < 2; ks++) {
      long row = (long)h * LPAD + qi * BLKSZ + wid * 32 + mt * 16 + lm;
      Qf[mt][ks] = *(const short8v*)(qrb + row * DD + ks * 32 + lg * 8);
    }

  f32x4 Oacc[4][2];
#pragma unroll
  for (int a = 0; a < 4; a++)
#pragma unroll
    for (int b = 0; b < 2; b++) { f32x4 z = {0.f, 0.f, 0.f, 0.f}; Oacc[a][b] = z; }
  float lrow0 = 0.f, lrow1 = 0.f;

  int sr = tid & 63;
  int sd0 = (tid >> 6) * 16;

  short8v pkA, pkB, pvA, pvB;
  {
    long src = (long)h * LPAD + (long)c0 * 64 + sr;
    const short8v* kp = (const short8v*)(krb + src * DD + sd0);
    const short8v* vp = (const short8v*)(vrb + src * DD + sd0);
    pkA = kp[0]; pkB = kp[1];
    pvA = vp[0]; pvB = vp[1];
  }

  for (int c = c0; c < c1; c++) {
    __syncthreads();
    {
      int sw = (sr & 7) << 3;
      *(short8v*)&Kt[sr * 64 + (sd0 ^ sw)] = pkA;
      *(short8v*)&Kt[sr * 64 + ((sd0 + 8) ^ sw)] = pkB;
#pragma unroll
      for (int i = 0; i < 8; i++) {
        Vt[(sd0 + i) * 68 + sr] = pvA[i];
        Vt[(sd0 + 8 + i) * 68 + sr] = pvB[i];
      }
    }
    __syncthreads();
    if (c + 1 < c1) {
      long src = (long)h * LPAD + (long)(c + 1) * 64 + sr;
      const short8v* kp = (const short8v*)(krb + src * DD + sd0);
      const short8v* vp = (const short8v*)(vrb + src * DD + sd0);
      pkA = kp[0]; pkB = kp[1];
      pvA = vp[0]; pvB = vp[1];
    }

    bool allfull = (c != HCHUNK - 1);

    short8v Kf[4][2];
#pragma unroll
    for (int nt = 0; nt < 4; nt++)
#pragma unroll
      for (int ks = 0; ks < 2; ks++)
        Kf[nt][ks] = *(short8v*)&Kt[(nt * 16 + lm) * 64 + ((ks * 32 + lg * 8) ^ ((lm & 7) << 3))];

    short8v Pf[2][2];
#pragma unroll
    for (int mt = 0; mt < 2; mt++) {
      f32x4 aq[4];
#pragma unroll
      for (int nt = 0; nt < 4; nt++) {
        f32x4 z = {0.f, 0.f, 0.f, 0.f};
        f32x4 a = __builtin_amdgcn_mfma_f32_16x16x32_bf16(Kf[nt][0], Qf[mt][0], z, 0, 0, 0);
        aq[nt] = __builtin_amdgcn_mfma_f32_16x16x32_bf16(Kf[nt][1], Qf[mt][1], a, 0, 0, 0);
      }
      float ps[16];
      if (allfull) {
#pragma unroll
        for (int nt = 0; nt < 4; nt++)
#pragma unroll
          for (int i = 0; i < 4; i++)
            ps[nt * 4 + i] = __expf(aq[nt][i] * SCALE);
      } else {
#pragma unroll
        for (int nt = 0; nt < 4; nt++) {
          int cc = LSEQ - 16 * (4 * c + nt);
          int cnt = cc <= 0 ? 0 : (cc >= 16 ? 16 : cc);
#pragma unroll
          for (int i = 0; i < 4; i++) {
            int kvr = lg * 4 + i;
            ps[nt * 4 + i] = (kvr < cnt) ? __expf(aq[nt][i] * SCALE) : 0.f;
          }
        }
      }
      float lsum = 0.f;
#pragma unroll
      for (int i = 0; i < 16; i++) lsum += ps[i];
      if (mt == 0) lrow0 += lsum; else lrow1 += lsum;
#pragma unroll
      for (int H = 0; H < 2; H++) {
        union { int i[4]; short8v v; } u;
        u.i[0] = cvtpk(ps[8 * H + 0], ps[8 * H + 1]);
        u.i[1] = cvtpk(ps[8 * H + 2], ps[8 * H + 3]);
        u.i[2] = cvtpk(ps[8 * H + 4], ps[8 * H + 5]);
        u.i[3] = cvtpk(ps[8 * H + 6], ps[8 * H + 7]);
        Pf[mt][H] = u.v;
      }
    }

#pragma unroll
    for (int mtp = 0; mtp < 4; mtp++) {
      int d68 = (mtp * 16 + lm) * 68;
#pragma unroll
      for (int H = 0; H < 2; H++) {
        short4 lo = *(short4*)&Vt[d68 + H * 32 + lg * 4];
        short4 hi = *(short4*)&Vt[d68 + H * 32 + 16 + lg * 4];
        short8v vf;
        vf[0] = lo.x; vf[1] = lo.y; vf[2] = lo.z; vf[3] = lo.w;
        vf[4] = hi.x; vf[5] = hi.y; vf[6] = hi.z; vf[7] = hi.w;
        Oacc[mtp][0] = __builtin_amdgcn_mfma_f32_16x16x32_bf16(vf, Pf[0][H], Oacc[mtp][0], 0, 0, 0);
        Oacc[mtp][1] = __builtin_amdgcn_mfma_f32_16x16x32_bf16(vf, Pf[1][H], Oacc[mtp][1], 0, 0, 0);
      }
    }
  }

  lrow0 += __shfl_xor(lrow0, 16); lrow0 += __shfl_xor(lrow0, 32);
  lrow1 += __shfl_xor(lrow1, 16); lrow1 += __shfl_xor(lrow1, 32);
  if (lg == 0) {
    plsum[(long)slot * BLKSZ + wid * 32 + lm] = lrow0;
    plsum[(long)slot * BLKSZ + wid * 32 + 16 + lm] = lrow1;
  }
#pragma unroll
  for (int mt = 0; mt < 2; mt++) {
    int lrow = wid * 32 + mt * 16 + lm;
    float* orow = part + ((long)slot * BLKSZ + lrow) * DD;
#pragma unroll
    for (int mtp = 0; mtp < 4; mtp++) {
      f32x4 o = Oacc[mtp][mt];
      *(float4*)(orow + mtp * 16 + lg * 4) = make_float4(o[0], o[1], o[2], o[3]);
    }
  }
}

// combine heavy partials -> out directly (via dstrow)
__global__ __launch_bounds__(256) void k_combine(
    const float* __restrict__ part, const float* __restrict__ plsum,
    const int* __restrict__ dstrow, float* __restrict__ out) {
  int hq = blockIdx.x;
  int h = hq >> 1;
  int qi = NBLK - 2 + (hq & 1);
  int t = threadIdx.x;
  int row = t >> 1;
  int dbase = (t & 1) * 32;
  float l = 0.f;
  for (int s = 0; s < NSPLIT; s++) l += plsum[(long)(hq * NSPLIT + s) * BLKSZ + row];
  int grow = qi * BLKSZ + row;
  if (grow >= LSEQ) return;
  int dr = dstrow[grow];
  if (dr < 0) return;
  float inv = 1.0f / l;
  float* orow = out + ((long)h * LSEQ + dr) * DD;
  for (int d = dbase; d < dbase + 32; d += 4) {
    float4 acc = make_float4(0.f, 0.f, 0.f, 0.f);
    for (int s = 0; s < NSPLIT; s++) {
      float4 p4 = *(const float4*)&part[((long)(hq * NSPLIT + s) * BLKSZ + row) * DD + d];
      acc.x += p4.x; acc.y += p4.y; acc.z += p4.z; acc.w += p4.w;
    }
    *(float4*)(orow + d) = make_float4(acc.x * inv, acc.y * inv, acc.z * inv, acc.w * inv);
  }
}

// duplicate-row fixup: out[h][dst] = out[h][src] for host-built pairs
__global__ __launch_bounds__(64) void k_fixup(
    const int* __restrict__ duppairs, float* __restrict__ out, int nd) {
  int bid = blockIdx.x;       // dup*NH + h
  int h = bid & (NH - 1);
  int dup = bid >> 3;
  if (dup >= nd) return;
  int rdst = duppairs[2 * dup];
  int rsrc = duppairs[2 * dup + 1];
  out[((long)h * LSEQ + rdst) * DD + threadIdx.x] =
      out[((long)h * LSEQ + rsrc) * DD + threadIdx.x];
}

// ============================ launch ============================

extern "C" void kernel_launch(void* const* d_in, const int* in_sizes, int n_in,
                              void* d_out, int out_size, void* d_ws, size_t ws_size,
                              hipStream_t stream) {
  (void)in_sizes; (void)n_in; (void)out_size; (void)ws_size;
  const float* q = (const float*)d_in[0];
  const float* k = (const float*)d_in[1];
  const float* v = (const float*)d_in[2];
  float* ws = (float*)d_ws;
  float* out = (float*)d_out;

  static int* htab = nullptr;
  if (!htab) { (void)hipHostMalloc((void**)&htab, TAB_MAX * sizeof(int)); }
  build_tables(htab);
  int ndup = g_ndup;

  int* dtab = (int*)(ws + F_TB);
  int* inmap = dtab;
  int* dstrow = dtab + LSEQ;
  int* qidx = dtab + 2 * LSEQ;
  int* kidx = qidx + NH * NKEEP;
  int* duppairs = kidx + NH * NKEEP;
  int* dmask = (int*)(ws + F_MK);
  short* qrb = (short*)(ws + F_QB);
  short* krb = (short*)(ws + F_KB);
  short* vrb = (short*)(ws + F_VB);
  short* sqh = (short*)(ws + F_SQH);
  short* sqm = (short*)(ws + F_SQM);
  short* sql = (short*)(ws + F_SQL);
  short* skh = (short*)(ws + F_SKH);
  short* skm = (short*)(ws + F_SKM);
  short* skl = (short*)(ws + F_SKL);
  short* Kpb = (short*)(ws + F_KPB);
  short* Vpb = (short*)(ws + F_VPB);
  short* kfAll = (short*)(ws + F_KFA);
  short* vfAll = (short*)(ws + F_VFA);
  float* pool = ws + F_PL;
  float* part = ws + F_PT;
  float* plsum = ws + F_PS;

  hipMemcpyAsync(dtab, htab,
                 (size_t)(2 * LSEQ + 2 * NH * NKEEP + 2 * ndup) * sizeof(int),
                 hipMemcpyHostToDevice, stream);

  {
    long thr = 3L * NH * LPAD * 8;
    k_rearr<<<dim3((unsigned)((thr + 255) / 256)), 256, 0, stream>>>(
        q, k, v, qrb, krb, vrb, inmap);
  }
  {
    long thr = 2L * NH * NS * 8;
    k_sample<<<dim3((unsigned)((thr + 255) / 256)), 256, 0, stream>>>(
        q, k, sqh, sqm, sql, skh, skm, skl, qidx, kidx, inmap);
  }
  k_scores_pool<<<dim3(NH * NBLK), 256, 0, stream>>>(
      sqh, sqm, sql, skh, skm, skl, pool);
  k_mask<<<dim3(NH * NBLK), 192, 0, stream>>>(pool, dmask);
  {
    long rows = 2L * NH * NBLK * 112;
    k_poolkv<<<dim3((unsigned)((rows + 3) / 4)), 256, 0, stream>>>(krb, vrb, Kpb, Vpb);
  }
  {
    long thr = (long)NGALL * 128;
    k_fragk<<<dim3((unsigned)((thr + 255) / 256)), 256, 0, stream>>>(krb, Kpb, kfAll);
  }
  {
    long thr = (long)NGALL * 256;
    k_fragv<<<dim3((unsigned)((thr + 255) / 256)), 256, 0, stream>>>(vrb, Vpb, vfAll);
  }
  k_attn_heavy<<<dim3(NHEAVYB), 256, 0, stream>>>(qrb, krb, vrb, part, plsum);
  k_attn_light<<<dim3(NLIGHT2), 256, 0, stream>>>(qrb, kfAll, vfAll, dmask, dstrow, out);
  k_combine<<<dim3(NH * 2), 256, 0, stream>>>(part, plsum, dstrow, out);
  if (ndup > 0) {
    k_fixup<<<dim3((unsigned)(ndup * NH)), 64, 0, stream>>>(duppairs, out, ndup);
  }
}